// Round 9
// baseline (275.603 us; speedup 1.0000x reference)
//
#include <hip/hip_runtime.h>

#define CDIM 512
#define NH 8
#define HWDIM 4096
#define TPOS 64     // positions per tile (lane owns 1)
#define NTILE 4     // tiles per block
#define NT 512      // 8 waves: 4 reader + 4 writer

// Fold weights: wvT[c*8+n] = sum_j wqkv[(1024+64n+j)*512 + c]
//               wp [o*8+n] = sum_j wproj[o*512 + 64n + j]
__global__ __launch_bounds__(256) void prep_kernel(
    const float* __restrict__ wqkv, const float* __restrict__ wproj,
    float* __restrict__ wvT, float* __restrict__ wp) {
  int idx = blockIdx.x * 256 + threadIdx.x;
  if (idx < 4096) {
    int c = idx >> 3, n = idx & 7;
    const float* p = wqkv + (size_t)(1024 + n * 64) * CDIM + c;
    float s = 0.f;
#pragma unroll 8
    for (int j = 0; j < 64; ++j) s += p[(size_t)j * CDIM];
    wvT[idx] = s;
  } else if (idx < 8192) {
    int i2 = idx - 4096;
    int o = i2 >> 3, n = i2 & 7;
    const float* p = wproj + (size_t)o * CDIM + n * 64;
    float s = 0.f;
#pragma unroll 8
    for (int j = 0; j < 64; ++j) s += p[j];
    wp[i2] = s;
  }
}

// Wave-specialized R/W overlap. Reads are MSHR-bound at ~2.4 TB/s (proven
// invariant R0-R8); writes run at ~6.5 TB/s. Previous kernels serialized
// 53us of reads + 20us of writes in a device-wide phase convoy. Here waves
// 0-3 ONLY read (128 channels each) and waves 4-7 ONLY write (128 outputs
// each), pipelined over 4 tiles via double-buffered LDS partials — separate
// wave instruction streams let the CU issue loads and stores concurrently
// (per-wave VMEM is in-order, which killed the R7 interleave attempt).
__global__ __launch_bounds__(NT, 1) void fused_kernel(
    const float* __restrict__ x, const float* __restrict__ bias,
    const float* __restrict__ wvT, const float* __restrict__ wp,
    float* __restrict__ y) {
  __shared__ __align__(16) float sWv[4096];              // [c][n]  16KB
  __shared__ __align__(16) float sWp[4096];              // [o][n]  16KB
  __shared__ __align__(16) float sB[512];                //          2KB
  __shared__ __align__(16) float sS[2][4][NH][TPOS];     // dbuf partials 8KB

  const int t = threadIdx.x;
  for (int i = t; i < 4096; i += NT) { sWv[i] = wvT[i]; sWp[i] = wp[i]; }
  if (t < 512) sB[t] = bias[t];
  __syncthreads();

  const int wave = t >> 6;
  const int lane = t & 63;
  const int pos0 = blockIdx.x * (NTILE * TPOS);   // 256 | 4096: no b straddle
  const int b = pos0 >> 12;
  const int hw0 = pos0 & (HWDIM - 1);
  const float* xb = x + ((size_t)b * CDIM) * HWDIM + hw0 + lane;
  float* yb = y + ((size_t)b * CDIM) * HWDIM + hw0 + lane;

  const bool reader = (wave < 4);
  const int c0 = wave * 128;          // reader channel slice
  const int o0 = (wave - 4) * 128;    // writer output slice

  // Uniform barrier structure: NTILE+1 iterations, everyone hits each barrier.
  for (int tt = 0; tt <= NTILE; ++tt) {
    if (reader) {
      if (tt < NTILE) {
        const float* xt = xb + tt * TPOS;
        float acc[NH];
#pragma unroll
        for (int n = 0; n < NH; ++n) acc[n] = 0.f;
        for (int g = 0; g < 8; ++g) {
          float xv[16];
#pragma unroll
          for (int j = 0; j < 16; ++j)
            xv[j] = xt[(size_t)(c0 + g * 16 + j) * HWDIM];
#pragma unroll
          for (int j = 0; j < 16; ++j) {
            const int c = c0 + g * 16 + j;
            const float4 w0 = *(const float4*)&sWv[c * 8];
            const float4 w1 = *(const float4*)&sWv[c * 8 + 4];
            acc[0] = fmaf(w0.x, xv[j], acc[0]); acc[1] = fmaf(w0.y, xv[j], acc[1]);
            acc[2] = fmaf(w0.z, xv[j], acc[2]); acc[3] = fmaf(w0.w, xv[j], acc[3]);
            acc[4] = fmaf(w1.x, xv[j], acc[4]); acc[5] = fmaf(w1.y, xv[j], acc[5]);
            acc[6] = fmaf(w1.z, xv[j], acc[6]); acc[7] = fmaf(w1.w, xv[j], acc[7]);
          }
        }
        const int buf = tt & 1;
#pragma unroll
        for (int n = 0; n < NH; ++n) sS[buf][wave][n][lane] = acc[n];
      }
    } else {
      if (tt >= 1) {
        const int p = (tt - 1) & 1;
        float S2[NH];
#pragma unroll
        for (int n = 0; n < NH; ++n)
          S2[n] = sS[p][0][n][lane] + sS[p][1][n][lane] +
                  sS[p][2][n][lane] + sS[p][3][n][lane];
        float* yt = yb + (tt - 1) * TPOS;
#pragma unroll 4
        for (int oo = 0; oo < 128; ++oo) {
          const int o = o0 + oo;
          const float4 p0 = *(const float4*)&sWp[o * 8];
          const float4 p1 = *(const float4*)&sWp[o * 8 + 4];
          float r = sB[o];
          r = fmaf(p0.x, S2[0], r); r = fmaf(p0.y, S2[1], r);
          r = fmaf(p0.z, S2[2], r); r = fmaf(p0.w, S2[3], r);
          r = fmaf(p1.x, S2[4], r); r = fmaf(p1.y, S2[5], r);
          r = fmaf(p1.z, S2[6], r); r = fmaf(p1.w, S2[7], r);
          __builtin_nontemporal_store(r, yt + (size_t)o * HWDIM);
        }
      }
    }
    __syncthreads();
  }
}

extern "C" void kernel_launch(void* const* d_in, const int* in_sizes, int n_in,
                              void* d_out, int out_size, void* d_ws, size_t ws_size,
                              hipStream_t stream) {
  const float* x     = (const float*)d_in[0];
  const float* wqkv  = (const float*)d_in[1];
  const float* wproj = (const float*)d_in[2];
  const float* bproj = (const float*)d_in[3];
  float* y = (float*)d_out;

  float* wvT = (float*)d_ws;        // 4096 floats
  float* wp  = wvT + 4096;          // 4096 floats (32 KB total scratch)

  prep_kernel<<<32, 256, 0, stream>>>(wqkv, wproj, wvT, wp);
  fused_kernel<<<(16 * HWDIM) / (NTILE * TPOS), NT, 0, stream>>>(x, bproj, wvT, wp, y);
}